// Round 5
// baseline (98.404 us; speedup 1.0000x reference)
//
#include <hip/hip_runtime.h>
#include <math.h>

#define NB 1024        // value buckets (monotone map => exact algorithm, R0-proven)
#define ST 1024        // sort-kernel threads (16 waves)
#define NF 16384       // fast-path n (compile-time constant => static reg indexing)
#define RPT 16         // NF / ST elements staged per thread
#define IPB 64         // i's per block  (grid = NF/IPB = 256 = one block per CU)
#define BLOCK 256      // fallback block size

__device__ __forceinline__ int bucket_of(float t) {
    int b = (int)((t + 6.0f) * (NB / 12.0f));   // monotone (non-decreasing) in t
    return min(max(b, 0), NB - 1);
}

// One kernel does EVERYTHING per block, redundantly (1 block/CU):
//   phase 1: stage all n (T, exp(theta)) into registers; LDS hist cnt[b]++,
//            sfx[b] += E  (value-bucket map; any skew is still CORRECT, only
//            the phase-4 member loop gets longer).
//   phase 2: block-local dual Hillis-Steele: cnt -> exclusive-prefix cursor,
//            sfx -> exclusive-suffix sum (R0's proven scan pattern).
//   phase 3: scatter to bucket-sorted LDS arrays via atomic cursors (after
//            this, cnt[b] == end offset of bucket b).
//   phase 4: 64 i's (wave 0): risk = sfx[b_i] (all buckets above) + exact
//            compare loop over bucket b_i members; term; shuffle reduce.
//   epilogue: partial[blk] plain store + fence + ticket; last block reads the
//            256 partials with coherent-point RMWs (64 lanes x 4) -> out.
// Work is O(n) per block => ~5-7 us total, replacing the n^2 VALU sweep.
__global__ __launch_bounds__(ST, 4) void surv_all(
        const float* __restrict__ theta, const float* __restrict__ T,
        const float* __restrict__ events,
        float* __restrict__ partial, int* __restrict__ ticket,
        float* __restrict__ out) {
    __shared__ float sT[NF];      // 64 KB  bucket-sorted T
    __shared__ float sE[NF];      // 64 KB  bucket-sorted E
    __shared__ int   cnt[NB];     // 4 KB   hist -> cursor -> bucket end
    __shared__ float sfx[NB];     // 4 KB   bucketE -> exclusive suffix
    __shared__ int   pci[ST];     // 4 KB   scan temp (prefix)
    __shared__ float pce[ST];     // 4 KB   scan temp (suffix)
    __shared__ int   last;

    const int tid = threadIdx.x;

    cnt[tid] = 0;
    sfx[tid] = 0.f;
    __syncthreads();

    // phase 1: stage + histogram
    float Ts[RPT], Es[RPT];
    #pragma unroll
    for (int r = 0; r < RPT; ++r) {
        const int j = tid + (r << 10);            // coalesced
        const float tv = T[j];
        const float ev = expf(theta[j]);
        Ts[r] = tv; Es[r] = ev;
        const int b = bucket_of(tv);
        atomicAdd(&cnt[b], 1);
        atomicAdd(&sfx[b], ev);
    }
    __syncthreads();

    // phase 2: dual scan (1 bucket per thread): prefix(cnt), suffix(sfx)
    const int   c = cnt[tid];
    const float e = sfx[tid];
    pci[tid] = c; pce[tid] = e;
    __syncthreads();
    for (int s = 1; s < ST; s <<= 1) {            // R0-proven barrier pattern
        const int   a = (tid >= s)     ? pci[tid - s] : 0;
        const float f = (tid + s < ST) ? pce[tid + s] : 0.f;
        __syncthreads();
        pci[tid] += a; pce[tid] += f;
        __syncthreads();
    }
    cnt[tid] = pci[tid] - c;      // exclusive prefix  (scatter cursor)
    sfx[tid] = pce[tid] - e;      // exclusive suffix  (sum of buckets > tid)
    __syncthreads();

    // phase 3: scatter into bucket-sorted order
    #pragma unroll
    for (int r = 0; r < RPT; ++r) {
        const int b = bucket_of(Ts[r]);
        const int pos = atomicAdd(&cnt[b], 1);
        sT[pos] = Ts[r];
        sE[pos] = Es[r];
    }
    __syncthreads();

    // phase 4: exact risk + term for this block's 64 i's (wave 0)
    float term = 0.f;
    if (tid < IPB) {
        const int i = blockIdx.x * IPB + tid;
        const float Ti = T[i];
        const int b  = bucket_of(Ti);
        const int p0 = b ? cnt[b - 1] : 0;        // cnt[x] == end of bucket x
        const int p1 = cnt[b];
        float risk = sfx[b];                      // buckets strictly above b
        for (int p = p0; p < p1; ++p)             // exact in-bucket compares
            risk += (sT[p] >= Ti) ? sE[p] : 0.f;
        term = (theta[i] - logf(risk)) * events[i];
        #pragma unroll
        for (int off = 32; off > 0; off >>= 1)
            term += __shfl_down(term, off, 64);
    }
    if (tid == 0) {
        partial[blockIdx.x] = term;               // plain store
        __threadfence();                          // release before ticket
        last = (atomicAdd(ticket, 1) == (int)gridDim.x - 1) ? 1 : 0;
    }
    __syncthreads();
    if (last && tid < 64) {                       // last block: final reduce
        float v = 0.f;
        #pragma unroll
        for (int k = 0; k < 4; ++k)               // 256 partials, RMW reads at
            v += atomicAdd(&partial[k * 64 + tid], 0.f);  // the coherent point
        #pragma unroll
        for (int off = 32; off > 0; off >>= 1)
            v += __shfl_down(v, off, 64);
        if (tid == 0) out[0] = -v / (float)NF;
    }
}

// ---------- brute-force fallback (generic n) ----------
__global__ void surv_partial_bf(const float* __restrict__ theta, const float* __restrict__ T,
                                const float* __restrict__ events, float* __restrict__ bsum, int n) {
    __shared__ float red[BLOCK];
    const int tid = threadIdx.x;
    const int i = blockIdx.x * BLOCK + tid;
    float term = 0.f;
    if (i < n) {
        const float Ti = T[i];
        float risk = 0.f;
        for (int j = 0; j < n; ++j)
            risk += (T[j] >= Ti) ? expf(theta[j]) : 0.f;
        term = (theta[i] - logf(risk)) * events[i];
    }
    red[tid] = term;
    __syncthreads();
    for (int s = BLOCK / 2; s > 0; s >>= 1) {
        if (tid < s) red[tid] += red[tid + s];
        __syncthreads();
    }
    if (tid == 0) bsum[blockIdx.x] = red[0];
}

__global__ void surv_final(const float* __restrict__ bsum, float* __restrict__ out,
                           int nblocks, int n) {
    float v = 0.f;
    for (int b = threadIdx.x; b < nblocks; b += 64) v += bsum[b];
    for (int off = 32; off > 0; off >>= 1) v += __shfl_down(v, off, 64);
    if (threadIdx.x == 0) out[0] = -v / (float)n;
}

extern "C" void kernel_launch(void* const* d_in, const int* in_sizes, int n_in,
                              void* d_out, int out_size, void* d_ws, size_t ws_size,
                              hipStream_t stream) {
    const float* theta  = (const float*)d_in[0];
    const float* T      = (const float*)d_in[1];
    const float* events = (const float*)d_in[2];
    float* out = (float*)d_out;
    const int n = in_sizes[0];                  // 16384

    // ws layout: ticket (4 B, memset to 0) | partial[NF/IPB]
    const size_t need = 4 + (size_t)(NF / IPB) * 4;
    const bool fast = (n == NF) && ((size_t)ws_size >= need);

    if (!fast) {
        const int nbi = (n + BLOCK - 1) / BLOCK;
        float* bsum = (float*)d_ws;
        surv_partial_bf<<<nbi, BLOCK, 0, stream>>>(theta, T, events, bsum, n);
        surv_final<<<1, 64, 0, stream>>>(bsum, out, nbi, n);
        return;
    }

    int*   ticket  = (int*)d_ws;
    float* partial = (float*)(ticket + 1);

    hipMemsetAsync(ticket, 0, 4, stream);        // graph-capture-safe (R0 precedent)
    surv_all<<<NF / IPB, ST, 0, stream>>>(theta, T, events, partial, ticket, out);
}

// Round 6
// 83.515 us; speedup vs baseline: 1.1783x; 1.1783x over previous
//
#include <hip/hip_runtime.h>
#include <math.h>

#define NF 16384        // fast-path n
#define NB 4096         // value buckets (monotone map => exact; R0/R5-proven)
#define NBLK 64         // worker blocks (co-resident: 64 << 256 CUs, 34 KB LDS)
#define TPB 256         // threads per block (NBLK*TPB == NF, one element/thread)
#define CHUNK (NB/TPB)  // 16 buckets per thread in the redundant scan
#define NZ (4 + 3*NB)   // meta words to zero: bar[2], ticket, accum, hcnt, hE, rel
#define BLOCK 256       // fallback block size

__device__ __forceinline__ int bucket_of(float t) {
    int b = (int)((t + 6.0f) * (NB / 12.0f));   // monotone (non-decreasing) in t
    return min(max(b, 0), NB - 1);
}

// K1: zero the meta region (replaces memset; poison-safe each graph replay).
__global__ void surv_zero(int* __restrict__ w) {
    int i = blockIdx.x * TPB + threadIdx.x;
    if (i < NZ) w[i] = 0;
}

// K2: whole pipeline, work DISTRIBUTED (R5's mistake was 256x redundant work;
// here only the cheap 4096-bucket scan is redundant), 2 in-kernel grid
// barriers (release-add / acquire-spin at agent scope: the acquire emits the
// XCD-L2 invalidate that makes post-barrier plain loads coherent).
__global__ __launch_bounds__(TPB) void surv_pipe(
        const float* __restrict__ theta, const float* __restrict__ T,
        const float* __restrict__ events,
        int* __restrict__ bar, int* __restrict__ ticket, float* __restrict__ accum,
        int* __restrict__ hcnt, float* __restrict__ hE, int* __restrict__ rel,
        float2* __restrict__ sorted, float* __restrict__ out) {
    __shared__ int   pfx[NB + 1];   // exclusive prefix of counts (+ total at NB)
    __shared__ float sfx[NB];       // exclusive suffix of bucket E-sums
    __shared__ int   sc[TPB];
    __shared__ float se[TPB];

    const int tid = threadIdx.x;
    const int i   = blockIdx.x * TPB + tid;

    // ---- phase A: element load + global atomic hist (32K atomics total) ----
    const float Ti = T[i];
    const float Ei = expf(theta[i]);
    const int   bi = bucket_of(Ti);
    atomicAdd(&hcnt[bi], 1);
    atomicAdd(&hE[bi], Ei);

    // ---- grid barrier 1 ----
    __syncthreads();
    if (tid == 0) {
        __hip_atomic_fetch_add(&bar[0], 1, __ATOMIC_RELEASE, __HIP_MEMORY_SCOPE_AGENT);
        while (__hip_atomic_load(&bar[0], __ATOMIC_ACQUIRE, __HIP_MEMORY_SCOPE_AGENT) < NBLK)
            __builtin_amdgcn_s_sleep(8);
    }
    __syncthreads();

    // ---- phase B: redundant block-local dual scan of the global hist ----
    // (ints => bitwise-identical pfx in every block, required for phase C)
    int lc[CHUNK]; float le[CHUNK];
    const int base = tid * CHUNK;
    int cs = 0; float es = 0.f;
    #pragma unroll
    for (int k = 0; k < CHUNK; ++k) {
        lc[k] = hcnt[base + k];
        le[k] = hE[base + k];
        cs += lc[k]; es += le[k];
    }
    sc[tid] = cs; se[tid] = es;
    __syncthreads();
    for (int s = 1; s < TPB; s <<= 1) {          // R0-proven barrier pattern
        int   a = (tid >= s)      ? sc[tid - s] : 0;
        float f = (tid + s < TPB) ? se[tid + s] : 0.f;
        __syncthreads();
        sc[tid] += a; se[tid] += f;
        __syncthreads();
    }
    {   int run = sc[tid] - cs;                  // exclusive prefix of chunk sums
        #pragma unroll
        for (int k = 0; k < CHUNK; ++k) { pfx[base + k] = run; run += lc[k]; }
        if (tid == TPB - 1) pfx[NB] = run;       // == n
    }
    {   float rs = se[tid] - es;                 // exclusive suffix of chunk sums
        #pragma unroll
        for (int k = CHUNK - 1; k >= 0; --k) { sfx[base + k] = rs; rs += le[k]; }
    }
    __syncthreads();

    // ---- phase C: scatter to global bucket-sorted float2 array ----
    const int pos = pfx[bi] + atomicAdd(&rel[bi], 1);
    sorted[pos] = make_float2(Ti, Ei);

    // ---- grid barrier 2 ----
    __syncthreads();
    if (tid == 0) {
        __hip_atomic_fetch_add(&bar[1], 1, __ATOMIC_RELEASE, __HIP_MEMORY_SCOPE_AGENT);
        while (__hip_atomic_load(&bar[1], __ATOMIC_ACQUIRE, __HIP_MEMORY_SCOPE_AGENT) < NBLK)
            __builtin_amdgcn_s_sleep(8);
    }
    __syncthreads();

    // ---- phase D: exact risk = buckets above + in-bucket exact compares ----
    float risk = sfx[bi];
    const int p1 = pfx[bi + 1];
    for (int p = pfx[bi]; p < p1; ++p) {         // ~19 avg members @ NB=4096
        float2 v = sorted[p];
        risk += (v.x >= Ti) ? v.y : 0.f;
    }
    float term = (theta[i] - logf(risk)) * events[i];

    // ---- block reduce (4 waves) + proven ticket epilogue ----
    #pragma unroll
    for (int off = 32; off > 0; off >>= 1) term += __shfl_down(term, off, 64);
    if ((tid & 63) == 0) se[tid >> 6] = term;    // se is free after the scan
    __syncthreads();
    if (tid == 0) {
        atomicAdd(accum, se[0] + se[1] + se[2] + se[3]);
        __threadfence();
        int t = atomicAdd(ticket, 1);
        if (t == NBLK - 1) {
            float tot = atomicAdd(accum, 0.f);   // RMW read at coherent point
            out[0] = -tot / (float)NF;
        }
    }
}

// ---------- brute-force fallback (generic n) ----------
__global__ void surv_partial_bf(const float* __restrict__ theta, const float* __restrict__ T,
                                const float* __restrict__ events, float* __restrict__ bsum, int n) {
    __shared__ float red[BLOCK];
    const int tid = threadIdx.x;
    const int i = blockIdx.x * BLOCK + tid;
    float term = 0.f;
    if (i < n) {
        const float Ti = T[i];
        float risk = 0.f;
        for (int j = 0; j < n; ++j)
            risk += (T[j] >= Ti) ? expf(theta[j]) : 0.f;
        term = (theta[i] - logf(risk)) * events[i];
    }
    red[tid] = term;
    __syncthreads();
    for (int s = BLOCK / 2; s > 0; s >>= 1) {
        if (tid < s) red[tid] += red[tid + s];
        __syncthreads();
    }
    if (tid == 0) bsum[blockIdx.x] = red[0];
}

__global__ void surv_final(const float* __restrict__ bsum, float* __restrict__ out,
                           int nblocks, int n) {
    float v = 0.f;
    for (int b = threadIdx.x; b < nblocks; b += 64) v += bsum[b];
    for (int off = 32; off > 0; off >>= 1) v += __shfl_down(v, off, 64);
    if (threadIdx.x == 0) out[0] = -v / (float)n;
}

extern "C" void kernel_launch(void* const* d_in, const int* in_sizes, int n_in,
                              void* d_out, int out_size, void* d_ws, size_t ws_size,
                              hipStream_t stream) {
    const float* theta  = (const float*)d_in[0];
    const float* T      = (const float*)d_in[1];
    const float* events = (const float*)d_in[2];
    float* out = (float*)d_out;
    const int n = in_sizes[0];                  // 16384

    // ws layout (words): sorted[NF] float2 (2*NF) | meta: bar[2], ticket,
    // accum, hcnt[NB], hE[NB], rel[NB]  (meta = NZ words, zeroed by K1)
    const size_t need = ((size_t)2 * NF + NZ) * 4;
    const bool fast = (n == NF) && ((size_t)ws_size >= need);

    if (!fast) {
        const int nbi = (n + BLOCK - 1) / BLOCK;
        float* bsum = (float*)d_ws;
        surv_partial_bf<<<nbi, BLOCK, 0, stream>>>(theta, T, events, bsum, n);
        surv_final<<<1, 64, 0, stream>>>(bsum, out, nbi, n);
        return;
    }

    float2* sorted = (float2*)d_ws;
    int*    meta   = (int*)d_ws + 2 * NF;
    int*    bar    = meta;
    int*    ticket = meta + 2;
    float*  accum  = (float*)(meta + 3);
    int*    hcnt   = meta + 4;
    float*  hE     = (float*)(meta + 4 + NB);
    int*    rel    = meta + 4 + 2 * NB;

    const int zb = (NZ + TPB - 1) / TPB;
    surv_zero<<<zb, TPB, 0, stream>>>(meta);
    surv_pipe<<<NBLK, TPB, 0, stream>>>(theta, T, events, bar, ticket, accum,
                                        hcnt, hE, rel, sorted, out);
}

// Round 7
// 83.315 us; speedup vs baseline: 1.1811x; 1.0024x over previous
//
#include <hip/hip_runtime.h>
#include <math.h>

#define NF 16384        // fast-path n
#define NB 4096         // value buckets (monotone map => exact; proven R0/R5/R6)
#define TPB 256         // threads per block
#define NBLK (NF/TPB)   // 64 blocks: one element per thread
#define CHUNK (NB/TPB)  // 16 buckets per thread in the block-local scan
#define NMETA (3*NB+1)  // memset region: cnt[NB], hE[NB], rel[NB], ticket
#define BLOCK 256       // fallback block size

__device__ __forceinline__ int bucket_of(float t) {
    int b = (int)((t + 6.0f) * (NB / 12.0f));   // monotone (non-decreasing) in t
    return min(max(b, 0), NB - 1);
}

// K1: histogram. 16K threads, one element each: E=exp(theta), global atomic
// hist (cnt, hE over 4096 buckets; ~4-way avg contention). Store Earr.
__global__ __launch_bounds__(TPB) void surv_hist(
        const float* __restrict__ theta, const float* __restrict__ T,
        float* __restrict__ Earr, int* __restrict__ cnt, float* __restrict__ hE) {
    const int i = blockIdx.x * TPB + threadIdx.x;
    const float Tv = T[i];
    const float Ev = expf(theta[i]);
    Earr[i] = Ev;
    const int b = bucket_of(Tv);
    atomicAdd(&cnt[b], 1);
    atomicAdd(&hE[b], Ev);
}

// K2: scan + scatter. Each of 64 blocks REDUNDANTLY scans the 4096-bucket
// hist in LDS (~1 us; int counts => bitwise-identical pfx in every block —
// the redundancy replaces a grid barrier, which R6 proved costs ~10 us).
// Block 0 publishes pfx/sfx for K3; every block scatters its own 256
// elements via pfx[b] + global atomic cursor.
__global__ __launch_bounds__(TPB) void surv_scan_scatter(
        const float* __restrict__ T, const float* __restrict__ Earr,
        const int* __restrict__ cnt, const float* __restrict__ hE,
        int* __restrict__ rel, int* __restrict__ pfxg, float* __restrict__ sfxg,
        float2* __restrict__ sorted) {
    __shared__ int   pfx[NB + 1];   // exclusive prefix of counts
    __shared__ float sfx[NB];       // exclusive suffix of bucket E-sums
    __shared__ int   sc[TPB];
    __shared__ float se[TPB];

    const int tid  = threadIdx.x;
    const int base = tid * CHUNK;

    int lc[CHUNK]; float le[CHUNK];
    int cs = 0; float es = 0.f;
    #pragma unroll
    for (int k = 0; k < CHUNK; ++k) {
        lc[k] = cnt[base + k];
        le[k] = hE[base + k];
        cs += lc[k]; es += le[k];
    }
    sc[tid] = cs; se[tid] = es;
    __syncthreads();
    for (int s = 1; s < TPB; s <<= 1) {          // proven dual Hillis-Steele
        int   a = (tid >= s)      ? sc[tid - s] : 0;
        float f = (tid + s < TPB) ? se[tid + s] : 0.f;
        __syncthreads();
        sc[tid] += a; se[tid] += f;
        __syncthreads();
    }
    {   int run = sc[tid] - cs;                  // exclusive prefix
        #pragma unroll
        for (int k = 0; k < CHUNK; ++k) { pfx[base + k] = run; run += lc[k]; }
        if (tid == TPB - 1) pfx[NB] = run;       // == n
    }
    {   float rs = se[tid] - es;                 // exclusive suffix
        #pragma unroll
        for (int k = CHUNK - 1; k >= 0; --k) { sfx[base + k] = rs; rs += le[k]; }
    }
    __syncthreads();

    if (blockIdx.x == 0) {                       // publish for K3
        for (int idx = tid; idx < NB + 1; idx += TPB) pfxg[idx] = pfx[idx];
        for (int idx = tid; idx < NB;     idx += TPB) sfxg[idx] = sfx[idx];
    }

    // scatter this block's 256 elements
    const int i = blockIdx.x * TPB + tid;
    const float Tv = T[i];
    const float Ev = Earr[i];
    const int b = bucket_of(Tv);
    const int pos = pfx[b] + atomicAdd(&rel[b], 1);
    sorted[pos] = make_float2(Tv, Ev);
}

// K3: exact risk = suffix of buckets above + short in-bucket compare loop
// (~4 avg members @ NB=4096); term; block reduce; proven ticket epilogue
// (64 parallel coherent-point RMW reads in the last block).
__global__ __launch_bounds__(TPB) void surv_risk(
        const float* __restrict__ theta, const float* __restrict__ T,
        const float* __restrict__ events,
        const int* __restrict__ pfxg, const float* __restrict__ sfxg,
        const float2* __restrict__ sorted,
        float* __restrict__ bsum, int* __restrict__ ticket,
        float* __restrict__ out) {
    __shared__ float ws4[TPB / 64];
    __shared__ int last;

    const int tid = threadIdx.x;
    const int i = blockIdx.x * TPB + tid;
    const float Tv = T[i];
    const int b = bucket_of(Tv);
    float r = sfxg[b];
    const int p1 = pfxg[b + 1];
    for (int p = pfxg[b]; p < p1; ++p) {
        float2 v = sorted[p];
        r += (v.x >= Tv) ? v.y : 0.f;
    }
    float term = (theta[i] - logf(r)) * events[i];

    #pragma unroll
    for (int off = 32; off > 0; off >>= 1) term += __shfl_down(term, off, 64);
    if ((tid & 63) == 0) ws4[tid >> 6] = term;
    __syncthreads();
    if (tid == 0) {
        bsum[blockIdx.x] = ws4[0] + ws4[1] + ws4[2] + ws4[3];  // plain store
        __threadfence();                                       // release
        last = (atomicAdd(ticket, 1) == NBLK - 1) ? 1 : 0;
    }
    __syncthreads();
    if (last && tid < 64) {                      // 64 parallel RMW reads at
        float v = atomicAdd(&bsum[tid], 0.f);    // the coherent point
        #pragma unroll
        for (int off = 32; off > 0; off >>= 1) v += __shfl_down(v, off, 64);
        if (tid == 0) out[0] = -v / (float)NF;
    }
}

// ---------- brute-force fallback (generic n) ----------
__global__ void surv_partial_bf(const float* __restrict__ theta, const float* __restrict__ T,
                                const float* __restrict__ events, float* __restrict__ bsum, int n) {
    __shared__ float red[BLOCK];
    const int tid = threadIdx.x;
    const int i = blockIdx.x * BLOCK + tid;
    float term = 0.f;
    if (i < n) {
        const float Ti = T[i];
        float risk = 0.f;
        for (int j = 0; j < n; ++j)
            risk += (T[j] >= Ti) ? expf(theta[j]) : 0.f;
        term = (theta[i] - logf(risk)) * events[i];
    }
    red[tid] = term;
    __syncthreads();
    for (int s = BLOCK / 2; s > 0; s >>= 1) {
        if (tid < s) red[tid] += red[tid + s];
        __syncthreads();
    }
    if (tid == 0) bsum[blockIdx.x] = red[0];
}

__global__ void surv_final(const float* __restrict__ bsum, float* __restrict__ out,
                           int nblocks, int n) {
    float v = 0.f;
    for (int b = threadIdx.x; b < nblocks; b += 64) v += bsum[b];
    for (int off = 32; off > 0; off >>= 1) v += __shfl_down(v, off, 64);
    if (threadIdx.x == 0) out[0] = -v / (float)n;
}

extern "C" void kernel_launch(void* const* d_in, const int* in_sizes, int n_in,
                              void* d_out, int out_size, void* d_ws, size_t ws_size,
                              hipStream_t stream) {
    const float* theta  = (const float*)d_in[0];
    const float* T      = (const float*)d_in[1];
    const float* events = (const float*)d_in[2];
    float* out = (float*)d_out;
    const int n = in_sizes[0];                  // 16384

    // ws layout (words):
    //   sorted float2[NF] (2NF) | Earr[NF] | pfxg[NB+1] | sfxg[NB] | bsum[NBLK]
    //   | meta (memset, NMETA words): cnt[NB], hE[NB], rel[NB], ticket
    const size_t need = ((size_t)3 * NF + (NB + 1) + NB + NBLK + NMETA) * 4;
    const bool fast = (n == NF) && ((size_t)ws_size >= need);

    if (!fast) {
        const int nbi = (n + BLOCK - 1) / BLOCK;
        float* bsum = (float*)d_ws;
        surv_partial_bf<<<nbi, BLOCK, 0, stream>>>(theta, T, events, bsum, n);
        surv_final<<<1, 64, 0, stream>>>(bsum, out, nbi, n);
        return;
    }

    float2* sorted = (float2*)d_ws;
    float*  Earr   = (float*)d_ws + 2 * NF;
    int*    pfxg   = (int*)(Earr + NF);
    float*  sfxg   = (float*)(pfxg + NB + 1);
    float*  bsum   = sfxg + NB;
    int*    meta   = (int*)(bsum + NBLK);
    int*    cnt    = meta;
    float*  hE     = (float*)(meta + NB);
    int*    rel    = meta + 2 * NB;
    int*    ticket = meta + 3 * NB;

    hipMemsetAsync(meta, 0, (size_t)NMETA * 4, stream);   // 48 KB, graph-safe
    surv_hist<<<NBLK, TPB, 0, stream>>>(theta, T, Earr, cnt, hE);
    surv_scan_scatter<<<NBLK, TPB, 0, stream>>>(T, Earr, cnt, hE, rel,
                                                pfxg, sfxg, sorted);
    surv_risk<<<NBLK, TPB, 0, stream>>>(theta, T, events, pfxg, sfxg, sorted,
                                        bsum, ticket, out);
}